// Round 6
// baseline (423.686 us; speedup 1.0000x reference)
//
#include <hip/hip_runtime.h>

#define TT 65536
#define R2 16384

typedef _Float16 f16x8 __attribute__((ext_vector_type(8)));
typedef float    f32x4 __attribute__((ext_vector_type(4)));
typedef unsigned u32x4 __attribute__((ext_vector_type(4)));

#define MFMA16 __builtin_amdgcn_mfma_f32_16x16x32_f16

// ---- helpers ----
__device__ __forceinline__ unsigned short f2h(float f){
    _Float16 h = (_Float16)f;
    return __builtin_bit_cast(unsigned short, h);
}
__device__ __forceinline__ float h2f(unsigned short u){
    return (float)__builtin_bit_cast(_Float16, u);
}
__device__ __forceinline__ unsigned relu2(unsigned w){
    unsigned s = w & 0x80008000u;
    unsigned mask = ((s >> 15) * 0x7FFFu) | s;
    return w & ~mask;
}
__device__ __forceinline__ float nrm(float a){
    float v = a / 1.101f + 0.5f;
    v = fmaxf(v, 0.0f);
    v = fminf(v, 0.99999f);
    return v;
}

// ---- repack weights f32 -> f16 B-fragment layout ----
// stream order per block i: W0(2 segs) | W1(1 seg) | Ws(2 segs); each seg 16384 f16
__global__ __launch_bounds__(256) void k_repack(const float* __restrict__ W0,
        const float* __restrict__ W1, const float* __restrict__ Ws,
        const float* __restrict__ Wc, unsigned short* __restrict__ out){
    int e = blockIdx.x*256 + threadIdx.x;
    const float* src; int r;
    if (e < 409600){
        int i = e / 81920; r = e % 81920;
        if (r < 32768)      { src = W0 + (size_t)i*32768; }
        else if (r < 49152) { src = W1 + (size_t)i*16384; r -= 32768; }
        else                { src = Ws + (size_t)i*32768; r -= 49152; }
    } else { src = Wc; r = e - 409600; }
    int j = r & 7, l = (r >> 3) & 63, t = (r >> 9) & 7, ks = r >> 12;
    int k = ks*32 + (l >> 4)*8 + j;
    int n = t*16 + (l & 15);
    out[e] = f2h(src[k*128 + n]);
}

// ---- indices + histogram (fused) ----
__global__ __launch_bounds__(256) void k_idxhist(const float* __restrict__ p,
        int* __restrict__ idx, int* __restrict__ cnt){
    int pt = blockIdx.x*256 + threadIdx.x;
    float p0 = p[pt*3+0], p1 = p[pt*3+1], p2 = p[pt*3+2];
    int g0 = (int)(nrm(p0)*128.f);
    int g1 = (int)(nrm(p1)*128.f);
    int g2 = (int)(nrm(p2)*128.f);
    int i0 = g0 + 128*g2, i1 = g0 + 128*g1, i2 = g1 + 128*g2;
    idx[0*TT + pt] = i0;
    idx[1*TT + pt] = i1;
    idx[2*TT + pt] = i2;
    int b14 = (pt >> 15) << 14;
    atomicAdd(&cnt[0*32768 + b14 + i0], 1);
    atomicAdd(&cnt[1*32768 + b14 + i1], 1);
    atomicAdd(&cnt[2*32768 + b14 + i2], 1);
}

// ---- exclusive scan (1 block of 1024 per plane); cnt may alias cp ----
__global__ __launch_bounds__(1024) void k_scan(const int* __restrict__ cnt,
        int* __restrict__ cs, int* __restrict__ cp){
    __shared__ int ls[1024];
    int pl = blockIdx.x, tid = threadIdx.x;
    const int* c = cnt + pl*32768;
    int v[32], tot = 0;
    #pragma unroll
    for (int j = 0; j < 32; j++){ v[j] = c[tid*32 + j]; tot += v[j]; }
    int x = tot;
    ls[tid] = x; __syncthreads();
    for (int off = 1; off < 1024; off <<= 1){
        int add = (tid >= off) ? ls[tid - off] : 0;
        __syncthreads();
        x += add; ls[tid] = x;
        __syncthreads();
    }
    int run = x - tot;
    #pragma unroll
    for (int j = 0; j < 32; j++){
        cs[pl*32769 + tid*32 + j] = run;
        cp[pl*32768 + tid*32 + j] = run;
        run += v[j];
    }
    if (tid == 1023) cs[pl*32769 + 32768] = TT;
}

// ---- counting sort: scatter point ids ----
__global__ __launch_bounds__(256) void k_scatter(const int* __restrict__ idx,
        int* __restrict__ cp, int* __restrict__ srt){
    int pt = blockIdx.x*256 + threadIdx.x;
    int b14 = (pt >> 15) << 14;
    #pragma unroll
    for (int pl = 0; pl < 3; pl++){
        int pos = atomicAdd(&cp[pl*32768 + b14 + idx[pl*TT + pt]], 1);
        srt[pl*TT + pos] = pt;
    }
}

// ---- per-cell max -> compact plane buffer mxp[pl][b*R2+cell][128] (f16) ----
__global__ __launch_bounds__(256) void k_pool3(const unsigned short* __restrict__ xb,
        const int* __restrict__ srt, const int* __restrict__ cs,
        unsigned short* __restrict__ mxp){
    int pl = blockIdx.y;
    const int* srtp = srt + (size_t)pl*TT;
    const int* csp  = cs  + (size_t)pl*32769;
    int lane = threadIdx.x & 63;
    int c = blockIdx.x*4 + (threadIdx.x >> 6);
    int s = csp[c], e = csp[c+1];
    if (s == e) return;
    float m0 = -1e30f, m1 = -1e30f;
    int pt = srtp[s];
    for (int i = s; i < e; i++){
        int ptn = (i+1 < e) ? srtp[i+1] : 0;
        unsigned v = ((const unsigned*)(xb + (size_t)pt*256))[lane];
        m0 = fmaxf(m0, h2f((unsigned short)(v & 0xFFFF)));
        m1 = fmaxf(m1, h2f((unsigned short)(v >> 16)));
        pt = ptn;
    }
    unsigned pk = (unsigned)f2h(m0) | ((unsigned)f2h(m1) << 16);
    ((unsigned*)(mxp + ((size_t)pl*32768 + c)*128))[lane] = pk;
}

// one K=32 slab: prefetch next 8 B-frags while 16 MFMAs consume current 8
#define SEG(ACC, CURB, NEXTB, GETA)                                   \
  { _Pragma("unroll")                                                 \
    for (int ks = 0; ks < 4; ks++){                                   \
      f16x8* cur = (ks & 1) ? bq1 : bq0;                              \
      f16x8* nxt = (ks & 1) ? bq0 : bq1;                              \
      const unsigned short* nb = (ks < 3) ? (CURB) : (NEXTB);         \
      int nks = (ks < 3) ? ks + 1 : 0;                                \
      if (nb) ld8(nxt, nb, nks);                                      \
      f16x8 a0, a1;                                                   \
      GETA                                                            \
      _Pragma("unroll")                                               \
      for (int t = 0; t < 8; t++){                                    \
        ACC[0][t] = MFMA16(a0, cur[t], ACC[0][t], 0, 0, 0);           \
        ACC[1][t] = MFMA16(a1, cur[t], ACC[1][t], 0, 0, 0);           \
      }                                                               \
    }                                                                 \
  }

#define A_RELU_XF { u32x4 u0 = xf[0][ks], u1 = xf[1][ks];                         \
    u0.x=relu2(u0.x); u0.y=relu2(u0.y); u0.z=relu2(u0.z); u0.w=relu2(u0.w);       \
    u1.x=relu2(u1.x); u1.y=relu2(u1.y); u1.z=relu2(u1.z); u1.w=relu2(u1.w);       \
    a0 = __builtin_bit_cast(f16x8, u0); a1 = __builtin_bit_cast(f16x8, u1); }
#define A_RELU_PF { u32x4 u0 = __builtin_bit_cast(u32x4, pf[0][ks]);              \
    u32x4 u1 = __builtin_bit_cast(u32x4, pf[1][ks]);                              \
    u0.x=relu2(u0.x); u0.y=relu2(u0.y); u0.z=relu2(u0.z); u0.w=relu2(u0.w);       \
    u1.x=relu2(u1.x); u1.y=relu2(u1.y); u1.z=relu2(u1.z); u1.w=relu2(u1.w);       \
    a0 = __builtin_bit_cast(f16x8, u0); a1 = __builtin_bit_cast(f16x8, u1); }
#define A_XF { a0 = __builtin_bit_cast(f16x8, xf[0][ks]);                         \
               a1 = __builtin_bit_cast(f16x8, xf[1][ks]); }
#define A_PF { a0 = pf[0][ks]; a1 = pf[1][ks]; }
#define A_LT { a0 = *(const f16x8*)&lt[((ks*8 + w*2 + 0)*64 + lane)*8];           \
               a1 = *(const f16x8*)&lt[((ks*8 + w*2 + 1)*64 + lane)*8]; }

// ---- fused ResnetBlockFC: barrier-free, B streamed from L2, LDS = wave-local lt ----
// pin != null : compute x fragments from p (first block); else read xb + gather mxp
// wc  != null : fuse fc_c, write c to xb cols 128..255 and skip net write
__global__ __launch_bounds__(256, 2) void k_resnet(unsigned short* __restrict__ xb,
        const unsigned short* __restrict__ wp,
        const float* __restrict__ b0, const float* __restrict__ b1,
        const int* __restrict__ idx, const unsigned short* __restrict__ mxp,
        const float* __restrict__ pin, const float* __restrict__ fW,
        const float* __restrict__ fb,
        const unsigned short* __restrict__ wc, const float* __restrict__ bc){
    __shared__ __align__(16) unsigned short lt[16384];   // 32 KB, wave-local strips
    int tid = threadIdx.x, w = tid >> 6, lane = tid & 63;
    int quad = lane >> 4, l15 = lane & 15;
    int m0 = blockIdx.x*128 + w*32;
    float b0v[8], b1v[8];
    #pragma unroll
    for (int t = 0; t < 8; t++){ b0v[t] = b0[t*16 + l15]; b1v[t] = b1[t*16 + l15]; }

    f16x8 bq0[8], bq1[8];
    auto ld8 = [&](f16x8* dst, const unsigned short* base, int ks){
        #pragma unroll
        for (int t = 0; t < 8; t++)
            dst[t] = *(const f16x8*)(base + ((size_t)((ks*8 + t)*64 + lane))*8);
    };

    ld8(bq0, wp, 0);   // segment 0 ks=0 in flight during A-fragment setup

    // ---- A fragments: xf = x cols 0..127, pf = pooled/cols 128..255 ----
    u32x4 xf[2][4]; f16x8 pf[2][4];
    if (pin){
        #pragma unroll
        for (int s = 0; s < 2; s++){
            int row = m0 + s*16 + l15;
            float p0 = pin[row*3+0], p1 = pin[row*3+1], p2 = pin[row*3+2];
            #pragma unroll
            for (int ks = 0; ks < 4; ks++){
                int c0 = ks*32 + quad*8;
                unsigned short hx[8], hp[8];
                #pragma unroll
                for (int h = 0; h < 2; h++){
                    f32x4 w0 = *(const f32x4*)(fW + c0 + h*4);
                    f32x4 w1 = *(const f32x4*)(fW + 256 + c0 + h*4);
                    f32x4 w2 = *(const f32x4*)(fW + 512 + c0 + h*4);
                    f32x4 bb = *(const f32x4*)(fb + c0 + h*4);
                    f32x4 v0 = *(const f32x4*)(fW + 128 + c0 + h*4);
                    f32x4 v1 = *(const f32x4*)(fW + 384 + c0 + h*4);
                    f32x4 v2 = *(const f32x4*)(fW + 640 + c0 + h*4);
                    f32x4 bp = *(const f32x4*)(fb + 128 + c0 + h*4);
                    #pragma unroll
                    for (int j = 0; j < 4; j++){
                        hx[h*4+j] = f2h(bb[j] + p0*w0[j] + p1*w1[j] + p2*w2[j]);
                        hp[h*4+j] = f2h(bp[j] + p0*v0[j] + p1*v1[j] + p2*v2[j]);
                    }
                }
                unsigned short* dx = (unsigned short*)&xf[s][ks];
                unsigned short* dp = (unsigned short*)&pf[s][ks];
                #pragma unroll
                for (int j = 0; j < 8; j++){ dx[j] = hx[j]; dp[j] = hp[j]; }
            }
        }
    } else {
        #pragma unroll
        for (int s = 0; s < 2; s++){
            size_t rb = (size_t)(m0 + s*16 + l15)*256;
            #pragma unroll
            for (int ks = 0; ks < 4; ks++)
                xf[s][ks] = *(const u32x4*)(xb + rb + ks*32 + quad*8);
        }
        #pragma unroll
        for (int s = 0; s < 2; s++){
            int row = m0 + s*16 + l15;
            int b14 = (row >> 15) << 14;
            const unsigned short* q0 = mxp + ((size_t)(0*32768 + b14 + idx[row]))*128;
            const unsigned short* q1 = mxp + ((size_t)(1*32768 + b14 + idx[TT + row]))*128;
            const unsigned short* q2 = mxp + ((size_t)(2*32768 + b14 + idx[2*TT + row]))*128;
            #pragma unroll
            for (int ks = 0; ks < 4; ks++){
                int col = ks*32 + quad*8;
                f16x8 a = *(const f16x8*)(q0 + col);
                f16x8 b = *(const f16x8*)(q1 + col);
                f16x8 c = *(const f16x8*)(q2 + col);
                f16x8 r;
                #pragma unroll
                for (int j = 0; j < 8; j++)
                    r[j] = (_Float16)((float)a[j] + (float)b[j] + (float)c[j]);
                pf[s][ks] = r;
            }
        }
    }

    f32x4 acc[2][8];
    #pragma unroll
    for (int s = 0; s < 2; s++)
        #pragma unroll
        for (int t = 0; t < 8; t++){ f32x4 z = {0.f,0.f,0.f,0.f}; acc[s][t] = z; }

    // ---- GEMM1: relu(x) @ W0 over K=256 (segments 0,1) ----
    SEG(acc, wp,         wp + 16384, A_RELU_XF)
    SEG(acc, wp + 16384, wp + 32768, A_RELU_PF)

    // ---- transform relu(net+b0) -> lt (wave-local strips; no barrier needed) ----
    #pragma unroll
    for (int s = 0; s < 2; s++){
        int strip = w*2 + s;
        #pragma unroll
        for (int t = 0; t < 8; t++){
            int ks2 = t >> 1;
            int l2b = ((t & 1)*2 + ((lane >> 3) & 1))*16 + quad*4;
            #pragma unroll
            for (int r = 0; r < 4; r++){
                float v = acc[s][t][r] + b0v[t];
                v = fmaxf(v, 0.f);
                lt[(((ks2*8 + strip)*64) + l2b + r)*8 + (lane & 7)] = f2h(v);
            }
        }
    }

    // ---- GEMM2: relu(net) @ W1 (segment 2), acc2 init b1 ----
    f32x4 acc2[2][8];
    #pragma unroll
    for (int s = 0; s < 2; s++)
        #pragma unroll
        for (int t = 0; t < 8; t++){ f32x4 iv = {b1v[t],b1v[t],b1v[t],b1v[t]}; acc2[s][t] = iv; }
    SEG(acc2, wp + 32768, wp + 49152, A_LT)

    // ---- GEMM3: shortcut x @ Ws (segments 3,4), accumulate into acc2 ----
    SEG(acc2, wp + 49152, wp + 65536, A_XF)
    SEG(acc2, wp + 65536, wc,         A_PF)

    if (!wc){
        #pragma unroll
        for (int s = 0; s < 2; s++)
            #pragma unroll
            for (int t = 0; t < 8; t++)
                #pragma unroll
                for (int r = 0; r < 4; r++){
                    int row = m0 + s*16 + quad*4 + r;
                    xb[(size_t)row*256 + t*16 + l15] = f2h(acc2[s][t][r]);
                }
        return;
    }

    // ---- fused fc_c: net -> lt (no relu, same-wave strips), GEMM (lt @ Wc) ----
    #pragma unroll
    for (int s = 0; s < 2; s++){
        int strip = w*2 + s;
        #pragma unroll
        for (int t = 0; t < 8; t++){
            int ks2 = t >> 1;
            int l2b = ((t & 1)*2 + ((lane >> 3) & 1))*16 + quad*4;
            #pragma unroll
            for (int r = 0; r < 4; r++)
                lt[(((ks2*8 + strip)*64) + l2b + r)*8 + (lane & 7)] = f2h(acc2[s][t][r]);
        }
    }
    f32x4 acc3[2][8];
    #pragma unroll
    for (int t = 0; t < 8; t++){
        float bv = bc[t*16 + l15];
        f32x4 iv = {bv, bv, bv, bv};
        acc3[0][t] = iv; acc3[1][t] = iv;
    }
    SEG(acc3, wc, (const unsigned short*)nullptr, A_LT)
    #pragma unroll
    for (int s = 0; s < 2; s++)
        #pragma unroll
        for (int t = 0; t < 8; t++)
            #pragma unroll
            for (int r = 0; r < 4; r++){
                int row = m0 + s*16 + quad*4 + r;
                xb[(size_t)row*256 + 128 + t*16 + l15] = f2h(acc3[s][t][r]);
            }
}

// ---- scatter-mean + transpose, all planes in one launch ----
__global__ __launch_bounds__(1024) void k_psum3(const unsigned short* __restrict__ xb,
        const int* __restrict__ srt, const int* __restrict__ cs,
        float* __restrict__ out){
    __shared__ float ls[32*129];
    int pl = blockIdx.y;
    const int* srtp = srt + (size_t)pl*TT;
    const int* csp  = cs  + (size_t)pl*32769;
    int w = threadIdx.x >> 6, lane = threadIdx.x & 63;
    int c0 = blockIdx.x * 32;
    #pragma unroll
    for (int cc = w; cc < 32; cc += 16){
        int c = c0 + cc;
        int s = csp[c], e = csp[c+1];
        float s0 = 0.f, s1 = 0.f;
        if (s < e){
            int pt = srtp[s];
            for (int i = s; i < e; i++){
                int ptn = (i+1 < e) ? srtp[i+1] : 0;
                unsigned v = ((const unsigned*)(xb + (size_t)pt*256 + 128))[lane];
                s0 += h2f((unsigned short)(v & 0xFFFF));
                s1 += h2f((unsigned short)(v >> 16));
                pt = ptn;
            }
        }
        float rc = (e > s) ? 1.f/(float)(e - s) : 0.f;
        ls[cc*129 + lane*2]     = s0*rc;
        ls[cc*129 + lane*2 + 1] = s1*rc;
    }
    __syncthreads();
    int pb = pl*2 + (c0 >> 14);
    float* o = out + (size_t)pb*128*R2 + (c0 & 16383);
    #pragma unroll
    for (int j = 0; j < 4; j++){
        int lin = j*1024 + threadIdx.x;
        int f = lin >> 5, cc = lin & 31;
        o[(size_t)f*R2 + cc] = ls[cc*129 + f];
    }
}

extern "C" void kernel_launch(void* const* d_in, const int* in_sizes, int n_in,
                              void* d_out, int out_size, void* d_ws, size_t ws_size,
                              hipStream_t stream) {
    const float* p        = (const float*)d_in[0];
    const float* fc_pos_W = (const float*)d_in[1];
    const float* fc_pos_b = (const float*)d_in[2];
    const float* bW0      = (const float*)d_in[3];
    const float* bb0      = (const float*)d_in[4];
    const float* bW1      = (const float*)d_in[5];
    const float* bb1      = (const float*)d_in[6];
    const float* bWs      = (const float*)d_in[7];
    const float* fc_c_W   = (const float*)d_in[8];
    const float* fc_c_b   = (const float*)d_in[9];
    float* out = (float*)d_out;

    char* ws = (char*)d_ws;
    int*            idx   = (int*)ws;                          // 786,432 B
    unsigned short* xbuf  = (unsigned short*)(ws + 786432);    // 33,554,432 B
    int*            srt   = (int*)(ws + 34340864);             // 786,432 B
    int*            cs    = (int*)(ws + 35127296);             // 393,232 B
    int*            cp    = (int*)(ws + 35520528);             // 393,216 B
    unsigned short* wpack = (unsigned short*)(ws + 35913744);  // 851,968 B
    unsigned short* mxp   = (unsigned short*)(ws + 36765712);  // 25,165,824 B

    k_repack<<<1664, 256, 0, stream>>>(bW0, bW1, bWs, fc_c_W, wpack);
    hipMemsetAsync(cp, 0, (size_t)3*32768*4, stream);
    k_idxhist<<<TT/256, 256, 0, stream>>>(p, idx, cp);
    k_scan   <<<3, 1024, 0, stream>>>(cp, cs, cp);
    k_scatter<<<TT/256, 256, 0, stream>>>(idx, cp, srt);

    // resnet 1: fc_pos fused (pin path)
    k_resnet<<<512, 256, 0, stream>>>(xbuf, wpack, bb0, bb1,
            idx, (const unsigned short*)nullptr,
            p, fc_pos_W, fc_pos_b,
            (const unsigned short*)nullptr, (const float*)nullptr);

    for (int i = 1; i < 5; i++){
        k_pool3<<<dim3(8192, 3), 256, 0, stream>>>(xbuf, srt, cs, mxp);
        const unsigned short* wc = (i == 4) ? (wpack + 409600) : (const unsigned short*)nullptr;
        const float* bcp = (i == 4) ? fc_c_b : (const float*)nullptr;
        k_resnet<<<512, 256, 0, stream>>>(xbuf, wpack + (size_t)i*81920,
                bb0 + (size_t)i*128, bb1 + (size_t)i*128,
                idx, mxp,
                (const float*)nullptr, (const float*)nullptr, (const float*)nullptr,
                wc, bcp);
    }

    k_psum3<<<dim3(1024, 3), 1024, 0, stream>>>(xbuf, srt, cs, out);
}